// Round 2
// baseline (119.134 us; speedup 1.0000x reference)
//
#include <hip/hip_runtime.h>

#define B_    2
#define NFEAT 3
#define NCH   4
#define DIMX  18
#define NPT   (18*18*18)            /* 5832 */

#define IPT    4                    /* i-points per thread */
#define IBLK   (256*IPT)            /* 1024 i per block */
#define IB2    ((NPT + IBLK - 1)/IBLK)   /* 6 */
#define JS2    48                   /* j splits */
#define CHUNK2 ((NPT + JS2 - 1)/JS2)     /* 122, fits one LDS stage */

// sqrt(log2(e)) / ALPHA  (ALPHA == BETA == 5)
#define FSC   (1.2011224087864498f / 5.0f)

__device__ __forceinline__ float blockReduceSum(float v) {
  #pragma unroll
  for (int o = 32; o > 0; o >>= 1) v += __shfl_down(v, o, 64);
  __shared__ float red[4];
  int wid = threadIdx.x >> 6, lane = threadIdx.x & 63;
  if (lane == 0) red[wid] = v;
  __syncthreads();
  v = (threadIdx.x < 4) ? red[threadIdx.x] : 0.0f;
  if (wid == 0) {
    v += __shfl_down(v, 2, 64);
    v += __shfl_down(v, 1, 64);
  }
  return v;  // valid on thread 0
}

// P1 record (8 floats): f0..f5, q, pad   (features pre-scaled by sqrt(log2 e)/5)
// H  record (4 floats): softmax(U)
__global__ void prep_kernel(const float* __restrict__ I, const float* __restrict__ U,
                            float* __restrict__ P1, float* __restrict__ H) {
  int idx = blockIdx.x * blockDim.x + threadIdx.x;
  if (idx >= B_ * NPT) return;
  int b = idx / NPT, n = idx - b * NPT;
  int x = n / (DIMX * DIMX);
  int rem = n - x * DIMX * DIMX;
  int y = rem / DIMX, z = rem - y * DIMX;

  float f0 = x * FSC, f1 = y * FSC, f2 = z * FSC;
  float f3 = I[(size_t)(b * NFEAT + 0) * NPT + n] * FSC;
  float f4 = I[(size_t)(b * NFEAT + 1) * NPT + n] * FSC;
  float f5 = I[(size_t)(b * NFEAT + 2) * NPT + n] * FSC;
  float q = -0.5f * (f0*f0 + f1*f1 + f2*f2 + f3*f3 + f4*f4 + f5*f5);

  float4* P = (float4*)(P1 + (size_t)idx * 8);
  P[0] = make_float4(f0, f1, f2, f3);
  P[1] = make_float4(f4, f5, q, 0.0f);

  float u0 = U[(size_t)(b * NCH + 0) * NPT + n];
  float u1 = U[(size_t)(b * NCH + 1) * NPT + n];
  float u2 = U[(size_t)(b * NCH + 2) * NPT + n];
  float u3 = U[(size_t)(b * NCH + 3) * NPT + n];
  float m = fmaxf(fmaxf(u0, u1), fmaxf(u2, u3));
  float e0 = __expf(u0 - m), e1 = __expf(u1 - m), e2 = __expf(u2 - m), e3 = __expf(u3 - m);
  float inv = 1.0f / (e0 + e1 + e2 + e3);
  ((float4*)(H + (size_t)idx * 4))[0] = make_float4(e0*inv, e1*inv, e2*inv, e3*inv);
}

// Pass 1: s_i = sum_j exp2(min(q_i + q_j + f_i.f_j, 0)); 4 i's per thread.
__global__ void __launch_bounds__(256) pass1_kernel(const float* __restrict__ P1,
                                                    float* __restrict__ part) {
  __shared__ float4 sh[CHUNK2 * 2];
  int b = blockIdx.z;
  const float4* Pb = (const float4*)(P1 + (size_t)b * NPT * 8);

  float fi[IPT][7];
  int ibase = blockIdx.x * IBLK + threadIdx.x;
  #pragma unroll
  for (int m = 0; m < IPT; ++m) {
    int i = ibase + m * 256;
    int ic = i < NPT ? i : NPT - 1;
    float4 a0 = Pb[(size_t)ic * 2], a1 = Pb[(size_t)ic * 2 + 1];
    fi[m][0] = a0.x; fi[m][1] = a0.y; fi[m][2] = a0.z; fi[m][3] = a0.w;
    fi[m][4] = a1.x; fi[m][5] = a1.y; fi[m][6] = a1.z;
  }

  int jstart = blockIdx.y * CHUNK2;
  int jend = min(jstart + CHUNK2, NPT);
  int cnt = jend - jstart;
  if (threadIdx.x < cnt) {
    sh[threadIdx.x * 2]     = Pb[(size_t)(jstart + threadIdx.x) * 2];
    sh[threadIdx.x * 2 + 1] = Pb[(size_t)(jstart + threadIdx.x) * 2 + 1];
  }
  __syncthreads();

  float acc[IPT] = {0.0f, 0.0f, 0.0f, 0.0f};
  #pragma unroll 2
  for (int k = 0; k < cnt; ++k) {
    float4 fa = sh[k * 2], fb = sh[k * 2 + 1];
    #pragma unroll
    for (int m = 0; m < IPT; ++m) {
      float arg = (fi[m][6] + fb.z) + fi[m][0]*fa.x + fi[m][1]*fa.y + fi[m][2]*fa.z
                + fi[m][3]*fa.w + fi[m][4]*fb.x + fi[m][5]*fb.y;
      acc[m] += exp2f(fminf(arg, 0.0f));
    }
  }
  #pragma unroll
  for (int m = 0; m < IPT; ++m) {
    int i = ibase + m * 256;
    if (i < NPT) part[((size_t)b * JS2 + blockIdx.y) * NPT + i] = acc[m];
  }
}

// Finalize norm; V = H*norm, G = (1-H)*norm
__global__ void finalize_kernel(const float* __restrict__ H, const float* __restrict__ part,
                                float* __restrict__ V, float* __restrict__ G) {
  int idx = blockIdx.x * blockDim.x + threadIdx.x;
  if (idx >= B_ * NPT) return;
  int b = idx / NPT, i = idx - b * NPT;
  float s = 0.0f;
  #pragma unroll
  for (int k = 0; k < JS2; ++k) s += part[((size_t)b * JS2 + k) * NPT + i];
  float nrm = rsqrtf(s + 1e-20f);
  float4 h = ((const float4*)(H + (size_t)idx * 4))[0];
  ((float4*)(V + (size_t)idx * 4))[0] =
      make_float4(h.x * nrm, h.y * nrm, h.z * nrm, h.w * nrm);
  ((float4*)(G + (size_t)idx * 4))[0] =
      make_float4((1.0f - h.x) * nrm, (1.0f - h.y) * nrm, (1.0f - h.z) * nrm, (1.0f - h.w) * nrm);
}

// Pass 2: acc_c(i) = sum_j w_ij v_cj ; partial loss = sum_i sum_c acc_c g_ci
__global__ void __launch_bounds__(256) pass2_kernel(const float* __restrict__ P1,
                                                    const float* __restrict__ V,
                                                    const float* __restrict__ G,
                                                    float* __restrict__ partialLoss) {
  __shared__ float4 sh_f[CHUNK2 * 2];
  __shared__ float4 sh_v[CHUNK2];
  int b = blockIdx.z;
  const float4* Pb = (const float4*)(P1 + (size_t)b * NPT * 8);
  const float4* Vb = (const float4*)(V + (size_t)b * NPT * 4);
  const float4* Gb = (const float4*)(G + (size_t)b * NPT * 4);

  float fi[IPT][7];
  float4 g[IPT];
  int ibase = blockIdx.x * IBLK + threadIdx.x;
  #pragma unroll
  for (int m = 0; m < IPT; ++m) {
    int i = ibase + m * 256;
    int ic = i < NPT ? i : NPT - 1;
    float4 a0 = Pb[(size_t)ic * 2], a1 = Pb[(size_t)ic * 2 + 1];
    fi[m][0] = a0.x; fi[m][1] = a0.y; fi[m][2] = a0.z; fi[m][3] = a0.w;
    fi[m][4] = a1.x; fi[m][5] = a1.y; fi[m][6] = a1.z;
    float4 gg = Gb[ic];
    g[m] = (i < NPT) ? gg : make_float4(0.f, 0.f, 0.f, 0.f);
  }

  int jstart = blockIdx.y * CHUNK2;
  int jend = min(jstart + CHUNK2, NPT);
  int cnt = jend - jstart;
  if (threadIdx.x < cnt) {
    sh_f[threadIdx.x * 2]     = Pb[(size_t)(jstart + threadIdx.x) * 2];
    sh_f[threadIdx.x * 2 + 1] = Pb[(size_t)(jstart + threadIdx.x) * 2 + 1];
    sh_v[threadIdx.x]         = Vb[jstart + threadIdx.x];
  }
  __syncthreads();

  float a0_[IPT] = {0,0,0,0}, a1_[IPT] = {0,0,0,0}, a2_[IPT] = {0,0,0,0}, a3_[IPT] = {0,0,0,0};
  #pragma unroll 2
  for (int k = 0; k < cnt; ++k) {
    float4 fa = sh_f[k * 2], fb = sh_f[k * 2 + 1], fv = sh_v[k];
    #pragma unroll
    for (int m = 0; m < IPT; ++m) {
      float arg = (fi[m][6] + fb.z) + fi[m][0]*fa.x + fi[m][1]*fa.y + fi[m][2]*fa.z
                + fi[m][3]*fa.w + fi[m][4]*fb.x + fi[m][5]*fb.y;
      float w = exp2f(fminf(arg, 0.0f));
      a0_[m] += w * fv.x; a1_[m] += w * fv.y; a2_[m] += w * fv.z; a3_[m] += w * fv.w;
    }
  }

  float t_ = 0.0f;
  #pragma unroll
  for (int m = 0; m < IPT; ++m)
    t_ += a0_[m] * g[m].x + a1_[m] * g[m].y + a2_[m] * g[m].z + a3_[m] * g[m].w;
  float r = blockReduceSum(t_);
  if (threadIdx.x == 0)
    partialLoss[((size_t)b * JS2 + blockIdx.y) * IB2 + blockIdx.x] = r;
}

__global__ void reduce_kernel(const float* __restrict__ partialLoss, int n,
                              float* __restrict__ out) {
  float v = 0.0f;
  for (int k = threadIdx.x; k < n; k += 256) v += partialLoss[k];
  float r = blockReduceSum(v);
  if (threadIdx.x == 0) out[0] = r;
}

extern "C" void kernel_launch(void* const* d_in, const int* in_sizes, int n_in,
                              void* d_out, int out_size, void* d_ws, size_t ws_size,
                              hipStream_t stream) {
  const float* I = (const float*)d_in[0];
  const float* U = (const float*)d_in[1];
  float* out = (float*)d_out;
  float* ws = (float*)d_ws;

  size_t off = 0;
  float* P1 = ws + off;  off += (size_t)B_ * NPT * 8;
  float* H  = ws + off;  off += (size_t)B_ * NPT * 4;
  float* pt = ws + off;  off += (size_t)B_ * JS2 * NPT;
  float* V  = ws + off;  off += (size_t)B_ * NPT * 4;
  float* G  = ws + off;  off += (size_t)B_ * NPT * 4;
  float* pl = ws + off;  off += (size_t)B_ * JS2 * IB2;

  prep_kernel<<<(B_ * NPT + 255) / 256, 256, 0, stream>>>(I, U, P1, H);
  dim3 grid(IB2, JS2, B_);
  pass1_kernel<<<grid, 256, 0, stream>>>(P1, pt);
  finalize_kernel<<<(B_ * NPT + 255) / 256, 256, 0, stream>>>(H, pt, V, G);
  pass2_kernel<<<grid, 256, 0, stream>>>(P1, V, G, pl);
  reduce_kernel<<<1, 256, 0, stream>>>(pl, B_ * JS2 * IB2, out);
}

// Round 3
// 78.406 us; speedup vs baseline: 1.5194x; 1.5194x over previous
//
#include <hip/hip_runtime.h>

#define B_    2
#define NFEAT 3
#define NCH   4
#define DIMX  18
#define NPT   (18*18*18)            /* 5832 */

#define IPT    4                    /* i-points per thread */
#define IBLK   (256*IPT)            /* 1024 i per block */
#define IB2    ((NPT + IBLK - 1)/IBLK)   /* 6 */
#define JS2    85                   /* j splits -> 6*85*2 = 1020 blocks (~4/CU) */
#define CHUNK2 ((NPT + JS2 - 1)/JS2)     /* 69 */

// sqrt(log2(e)) / ALPHA  (ALPHA == BETA == 5)
#define FSC   (1.2011224087864498f / 5.0f)

#if __has_builtin(__builtin_amdgcn_exp2f)
#define EXP2(x) __builtin_amdgcn_exp2f(x)
#else
#define EXP2(x) exp2f(x)
#endif

#define EXPAND4(M) M(0) M(1) M(2) M(3)

__device__ __forceinline__ float blockReduceSum(float v) {
  #pragma unroll
  for (int o = 32; o > 0; o >>= 1) v += __shfl_down(v, o, 64);
  __shared__ float red[4];
  int wid = threadIdx.x >> 6, lane = threadIdx.x & 63;
  if (lane == 0) red[wid] = v;
  __syncthreads();
  v = (threadIdx.x < 4) ? red[threadIdx.x] : 0.0f;
  if (wid == 0) {
    v += __shfl_down(v, 2, 64);
    v += __shfl_down(v, 1, 64);
  }
  return v;  // valid on thread 0
}

// P1 record (8 floats): f0..f5, q, pad   (features pre-scaled by sqrt(log2 e)/5)
// H  record (4 floats): softmax(U)
__global__ void prep_kernel(const float* __restrict__ I, const float* __restrict__ U,
                            float* __restrict__ P1, float* __restrict__ H) {
  int idx = blockIdx.x * blockDim.x + threadIdx.x;
  if (idx >= B_ * NPT) return;
  int b = idx / NPT, n = idx - b * NPT;
  int x = n / (DIMX * DIMX);
  int rem = n - x * DIMX * DIMX;
  int y = rem / DIMX, z = rem - y * DIMX;

  float f0 = x * FSC, f1 = y * FSC, f2 = z * FSC;
  float f3 = I[(size_t)(b * NFEAT + 0) * NPT + n] * FSC;
  float f4 = I[(size_t)(b * NFEAT + 1) * NPT + n] * FSC;
  float f5 = I[(size_t)(b * NFEAT + 2) * NPT + n] * FSC;
  float q = -0.5f * (f0*f0 + f1*f1 + f2*f2 + f3*f3 + f4*f4 + f5*f5);

  float4* P = (float4*)(P1 + (size_t)idx * 8);
  P[0] = make_float4(f0, f1, f2, f3);
  P[1] = make_float4(f4, f5, q, 0.0f);

  float u0 = U[(size_t)(b * NCH + 0) * NPT + n];
  float u1 = U[(size_t)(b * NCH + 1) * NPT + n];
  float u2 = U[(size_t)(b * NCH + 2) * NPT + n];
  float u3 = U[(size_t)(b * NCH + 3) * NPT + n];
  float m = fmaxf(fmaxf(u0, u1), fmaxf(u2, u3));
  float e0 = __expf(u0 - m), e1 = __expf(u1 - m), e2 = __expf(u2 - m), e3 = __expf(u3 - m);
  float inv = 1.0f / (e0 + e1 + e2 + e3);
  ((float4*)(H + (size_t)idx * 4))[0] = make_float4(e0*inv, e1*inv, e2*inv, e3*inv);
}

// Pass 1: s_i = sum_j exp2(q_i + q_j + f_i.f_j); 4 i's per thread, named scalars.
__global__ void __launch_bounds__(256) pass1_kernel(const float* __restrict__ P1,
                                                    float* __restrict__ part) {
  __shared__ float4 sh[CHUNK2 * 2];
  int b = blockIdx.z;
  const float4* Pb = (const float4*)(P1 + (size_t)b * NPT * 8);
  int ibase = blockIdx.x * IBLK + threadIdx.x;

#define DECLI(m) float f0_##m, f1_##m, f2_##m, f3_##m, f4_##m, f5_##m, q_##m;
  EXPAND4(DECLI)
#define LOADI(m) { int i_ = ibase + m * 256; int ic_ = i_ < NPT ? i_ : NPT - 1; \
    float4 a0_ = Pb[(size_t)ic_ * 2], a1_ = Pb[(size_t)ic_ * 2 + 1]; \
    f0_##m = a0_.x; f1_##m = a0_.y; f2_##m = a0_.z; f3_##m = a0_.w; \
    f4_##m = a1_.x; f5_##m = a1_.y; q_##m = a1_.z; }
  EXPAND4(LOADI)

  int jstart = blockIdx.y * CHUNK2;
  int cnt = min(CHUNK2, NPT - jstart);
  if (threadIdx.x < cnt) {
    sh[threadIdx.x * 2]     = Pb[(size_t)(jstart + threadIdx.x) * 2];
    sh[threadIdx.x * 2 + 1] = Pb[(size_t)(jstart + threadIdx.x) * 2 + 1];
  }
  __syncthreads();

  float acc_0 = 0.f, acc_1 = 0.f, acc_2 = 0.f, acc_3 = 0.f;
#define BODY1(m) { float arg_ = (q_##m + fb.z) + f0_##m*fa.x + f1_##m*fa.y + f2_##m*fa.z \
      + f3_##m*fa.w + f4_##m*fb.x + f5_##m*fb.y; acc_##m += EXP2(arg_); }
  if (cnt == CHUNK2) {
    #pragma unroll 3
    for (int k = 0; k < CHUNK2; ++k) {
      float4 fa = sh[k * 2], fb = sh[k * 2 + 1];
      EXPAND4(BODY1)
    }
  } else {
    for (int k = 0; k < cnt; ++k) {
      float4 fa = sh[k * 2], fb = sh[k * 2 + 1];
      EXPAND4(BODY1)
    }
  }
#define STORE1(m) { int i_ = ibase + m * 256; \
    if (i_ < NPT) part[((size_t)b * JS2 + blockIdx.y) * NPT + i_] = acc_##m; }
  EXPAND4(STORE1)
}

// Finalize norm; V = H*norm, G = (1-H)*norm
__global__ void finalize_kernel(const float* __restrict__ H, const float* __restrict__ part,
                                float* __restrict__ V, float* __restrict__ G) {
  int idx = blockIdx.x * blockDim.x + threadIdx.x;
  if (idx >= B_ * NPT) return;
  int b = idx / NPT, i = idx - b * NPT;
  float s = 0.0f;
  for (int k = 0; k < JS2; ++k) s += part[((size_t)b * JS2 + k) * NPT + i];
  float nrm = rsqrtf(s + 1e-20f);
  float4 h = ((const float4*)(H + (size_t)idx * 4))[0];
  ((float4*)(V + (size_t)idx * 4))[0] =
      make_float4(h.x * nrm, h.y * nrm, h.z * nrm, h.w * nrm);
  ((float4*)(G + (size_t)idx * 4))[0] =
      make_float4((1.0f - h.x) * nrm, (1.0f - h.y) * nrm, (1.0f - h.z) * nrm, (1.0f - h.w) * nrm);
}

// Pass 2: acc_c(i) = sum_j w_ij v_cj ; partial loss = sum_i sum_c acc_c g_ci
__global__ void __launch_bounds__(256) pass2_kernel(const float* __restrict__ P1,
                                                    const float* __restrict__ V,
                                                    const float* __restrict__ G,
                                                    float* __restrict__ partialLoss) {
  __shared__ float4 sh_f[CHUNK2 * 2];
  __shared__ float4 sh_v[CHUNK2];
  int b = blockIdx.z;
  const float4* Pb = (const float4*)(P1 + (size_t)b * NPT * 8);
  const float4* Vb = (const float4*)(V + (size_t)b * NPT * 4);
  const float4* Gb = (const float4*)(G + (size_t)b * NPT * 4);
  int ibase = blockIdx.x * IBLK + threadIdx.x;

  EXPAND4(DECLI)
  EXPAND4(LOADI)
#define DECLG(m) float g0_##m, g1_##m, g2_##m, g3_##m;
  EXPAND4(DECLG)
#define LOADG(m) { int i_ = ibase + m * 256; int ic_ = i_ < NPT ? i_ : NPT - 1; \
    float4 gg_ = Gb[ic_]; bool v_ = i_ < NPT; \
    g0_##m = v_ ? gg_.x : 0.f; g1_##m = v_ ? gg_.y : 0.f; \
    g2_##m = v_ ? gg_.z : 0.f; g3_##m = v_ ? gg_.w : 0.f; }
  EXPAND4(LOADG)

  int jstart = blockIdx.y * CHUNK2;
  int cnt = min(CHUNK2, NPT - jstart);
  if (threadIdx.x < cnt) {
    sh_f[threadIdx.x * 2]     = Pb[(size_t)(jstart + threadIdx.x) * 2];
    sh_f[threadIdx.x * 2 + 1] = Pb[(size_t)(jstart + threadIdx.x) * 2 + 1];
    sh_v[threadIdx.x]         = Vb[jstart + threadIdx.x];
  }
  __syncthreads();

#define DECLA(m) float a0_##m = 0.f, a1_##m = 0.f, a2_##m = 0.f, a3_##m = 0.f;
  EXPAND4(DECLA)
#define BODY2(m) { float arg_ = (q_##m + fb.z) + f0_##m*fa.x + f1_##m*fa.y + f2_##m*fa.z \
      + f3_##m*fa.w + f4_##m*fb.x + f5_##m*fb.y; float w_ = EXP2(arg_); \
      a0_##m += w_ * fv.x; a1_##m += w_ * fv.y; a2_##m += w_ * fv.z; a3_##m += w_ * fv.w; }
  if (cnt == CHUNK2) {
    #pragma unroll 3
    for (int k = 0; k < CHUNK2; ++k) {
      float4 fa = sh_f[k * 2], fb = sh_f[k * 2 + 1], fv = sh_v[k];
      EXPAND4(BODY2)
    }
  } else {
    for (int k = 0; k < cnt; ++k) {
      float4 fa = sh_f[k * 2], fb = sh_f[k * 2 + 1], fv = sh_v[k];
      EXPAND4(BODY2)
    }
  }

  float t_ = 0.0f;
#define DOTG(m) t_ += a0_##m * g0_##m + a1_##m * g1_##m + a2_##m * g2_##m + a3_##m * g3_##m;
  EXPAND4(DOTG)
  float r = blockReduceSum(t_);
  if (threadIdx.x == 0)
    partialLoss[((size_t)b * JS2 + blockIdx.y) * IB2 + blockIdx.x] = r;
}

__global__ void reduce_kernel(const float* __restrict__ partialLoss, int n,
                              float* __restrict__ out) {
  float v = 0.0f;
  for (int k = threadIdx.x; k < n; k += 256) v += partialLoss[k];
  float r = blockReduceSum(v);
  if (threadIdx.x == 0) out[0] = r;
}

extern "C" void kernel_launch(void* const* d_in, const int* in_sizes, int n_in,
                              void* d_out, int out_size, void* d_ws, size_t ws_size,
                              hipStream_t stream) {
  const float* I = (const float*)d_in[0];
  const float* U = (const float*)d_in[1];
  float* out = (float*)d_out;
  float* ws = (float*)d_ws;

  size_t off = 0;
  float* P1 = ws + off;  off += (size_t)B_ * NPT * 8;
  float* H  = ws + off;  off += (size_t)B_ * NPT * 4;
  float* pt = ws + off;  off += (size_t)B_ * JS2 * NPT;
  float* V  = ws + off;  off += (size_t)B_ * NPT * 4;
  float* G  = ws + off;  off += (size_t)B_ * NPT * 4;
  float* pl = ws + off;  off += (size_t)B_ * JS2 * IB2;

  prep_kernel<<<(B_ * NPT + 255) / 256, 256, 0, stream>>>(I, U, P1, H);
  dim3 grid(IB2, JS2, B_);
  pass1_kernel<<<grid, 256, 0, stream>>>(P1, pt);
  finalize_kernel<<<(B_ * NPT + 255) / 256, 256, 0, stream>>>(H, pt, V, G);
  pass2_kernel<<<grid, 256, 0, stream>>>(P1, V, G, pl);
  reduce_kernel<<<1, 256, 0, stream>>>(pl, B_ * JS2 * IB2, out);
}

// Round 4
// 46.778 us; speedup vs baseline: 2.5468x; 1.6761x over previous
//
#include <hip/hip_runtime.h>

#define B_     2
#define NCH    4
#define DIMX   18
#define NPT    (18*18*18)        /* 5832 */
#define TIL    183               /* j-tiles of 32 covering NPT */
#define ITIL   184               /* i-tiles incl one pad tile */
#define NPTP   (ITIL*32)         /* 5888 */
#define IBLOCKS 46               /* ITIL/4 waves-per-block */
#define JSP    12                /* j splits */
#define FSC    (1.2011224087864498f / 5.0f)   /* sqrt(log2 e)/5 */
#define QPAD   -30000.0f

typedef __attribute__((ext_vector_type(8)))  short short8;
typedef __attribute__((ext_vector_type(4)))  short short4_;
typedef __attribute__((ext_vector_type(16))) float f32x16;
typedef __attribute__((ext_vector_type(4)))  int   int4_;

#define EXP2(x) __builtin_amdgcn_exp2f(x)
#define MFMA32(a, b, c) __builtin_amdgcn_mfma_f32_32x32x16_bf16(a, b, c, 0, 0, 0)

__device__ __forceinline__ unsigned short bf16rtn(float f) {
  unsigned u = __float_as_uint(f);
  u += 0x7fffu + ((u >> 16) & 1u);
  return (unsigned short)(u >> 16);
}
__device__ __forceinline__ float bf2f(unsigned short s) {
  return __uint_as_float(((unsigned)s) << 16);
}

__device__ __forceinline__ float blockReduceSum(float v) {
  #pragma unroll
  for (int o = 32; o > 0; o >>= 1) v += __shfl_down(v, o, 64);
  __shared__ float red[4];
  int wid = threadIdx.x >> 6, lane = threadIdx.x & 63;
  if (lane == 0) red[wid] = v;
  __syncthreads();
  v = (threadIdx.x < 4) ? red[threadIdx.x] : 0.0f;
  if (wid == 0) {
    v += __shfl_down(v, 2, 64);
    v += __shfl_down(v, 1, 64);
  }
  return v;  // valid on thread 0
}

// Per point: a = (f0..f5, q, 1), b = (f0..f5, 1, q); hi/lo bf16 split.
// AHI/ALO: short8 per point. BHL: [bhi | blo] short8 pair per point. H: softmax f32x4.
__global__ void prep_kernel(const float* __restrict__ I, const float* __restrict__ U,
                            short8* __restrict__ AHI, short8* __restrict__ ALO,
                            short8* __restrict__ BHL, float4* __restrict__ H) {
  int idx = blockIdx.x * 256 + threadIdx.x;
  if (idx >= B_ * NPTP) return;
  int bb = idx / NPTP, n = idx - bb * NPTP;
  short8 ahi, alo, bhi, blo;
  float4 hh;
  if (n < NPT) {
    int x = n / (DIMX * DIMX);
    int rem = n - x * DIMX * DIMX;
    int y = rem / DIMX, z = rem - y * DIMX;
    float f0 = x * FSC, f1 = y * FSC, f2 = z * FSC;
    float f3 = I[(size_t)(bb * 3 + 0) * NPT + n] * FSC;
    float f4 = I[(size_t)(bb * 3 + 1) * NPT + n] * FSC;
    float f5 = I[(size_t)(bb * 3 + 2) * NPT + n] * FSC;
    float q = -0.5f * (f0*f0 + f1*f1 + f2*f2 + f3*f3 + f4*f4 + f5*f5);
    float av[8] = {f0, f1, f2, f3, f4, f5, q, 1.0f};
    float bv[8] = {f0, f1, f2, f3, f4, f5, 1.0f, q};
    #pragma unroll
    for (int e = 0; e < 8; ++e) {
      unsigned short ah = bf16rtn(av[e]);
      ahi[e] = (short)ah;
      alo[e] = (short)bf16rtn(av[e] - bf2f(ah));
      unsigned short bh = bf16rtn(bv[e]);
      bhi[e] = (short)bh;
      blo[e] = (short)bf16rtn(bv[e] - bf2f(bh));
    }
    float u0 = U[(size_t)(bb * NCH + 0) * NPT + n];
    float u1 = U[(size_t)(bb * NCH + 1) * NPT + n];
    float u2 = U[(size_t)(bb * NCH + 2) * NPT + n];
    float u3 = U[(size_t)(bb * NCH + 3) * NPT + n];
    float m = fmaxf(fmaxf(u0, u1), fmaxf(u2, u3));
    float e0 = __expf(u0 - m), e1 = __expf(u1 - m), e2 = __expf(u2 - m), e3 = __expf(u3 - m);
    float inv = 1.0f / (e0 + e1 + e2 + e3);
    hh = make_float4(e0 * inv, e1 * inv, e2 * inv, e3 * inv);
  } else {
    #pragma unroll
    for (int e = 0; e < 8; ++e) { ahi[e] = 0; alo[e] = 0; bhi[e] = 0; blo[e] = 0; }
    bhi[7] = (short)bf16rtn(QPAD);   // pad j row: arg -> -3e4 -> w = 0
    hh = make_float4(0.f, 0.f, 0.f, 0.f);
  }
  AHI[idx] = ahi;
  ALO[idx] = alo;
  BHL[(size_t)idx * 2]     = bhi;
  BHL[(size_t)idx * 2 + 1] = blo;
  H[idx] = hh;
}

// Pass 1: swapped ARG = mfma(Fj, Fi): D[j][i]. s_i = sum over rows (regs + h-halves).
__global__ void __launch_bounds__(256) pass1_kernel(const short8* __restrict__ AHI,
                                                    const short8* __restrict__ ALO,
                                                    const short8* __restrict__ BHL,
                                                    float* __restrict__ part) {
  int tid = threadIdx.x, wid = tid >> 6, l = tid & 63, h = l >> 5, li = l & 31;
  int bb = blockIdx.z, ch = blockIdx.y;
  int it = blockIdx.x * 4 + wid;
  int i = it * 32 + li;
  size_t pbase = (size_t)bb * NPTP;

  short8 zer = {0, 0, 0, 0, 0, 0, 0, 0};
  short8 b1 = AHI[pbase + i];                 // B1: [a_hi | a_hi]
  short8 b2 = h ? zer : ALO[pbase + i];       // B2: [a_lo | 0]

  int t0 = ch * TIL / JSP, t1 = (ch + 1) * TIL / JSP;
  float sacc = 0.0f;
  for (int t = t0; t < t1; ++t) {
    int j = t * 32 + li;
    short8 a1 = BHL[(pbase + j) * 2 + h];     // A: [b_hi | b_lo]
    f32x16 acc;
    #pragma unroll
    for (int r = 0; r < 16; ++r) acc[r] = 0.0f;
    acc = MFMA32(a1, b1, acc);
    acc = MFMA32(a1, b2, acc);
    float ssum = 0.0f;
    #pragma unroll
    for (int r = 0; r < 16; ++r) ssum += EXP2(acc[r]);
    sacc += ssum;
  }
  sacc += __shfl_xor(sacc, 32, 64);
  if (h == 0) part[((size_t)bb * JSP + ch) * NPTP + i] = sacc;
}

// norm; Vt[c][j] = bf16(H*n) (c-major), G4[i] = (1-H)*n
__global__ void finalize_kernel(const float4* __restrict__ H, const float* __restrict__ part,
                                unsigned short* __restrict__ Vt, float4* __restrict__ G4) {
  int idx = blockIdx.x * 256 + threadIdx.x;
  if (idx >= B_ * NPTP) return;
  int bb = idx / NPTP, i = idx - bb * NPTP;
  if (i < NPT) {
    float s = 0.0f;
    #pragma unroll
    for (int k = 0; k < JSP; ++k) s += part[((size_t)bb * JSP + k) * NPTP + i];
    float nrm = rsqrtf(s + 1e-20f);
    float4 hh = H[idx];
    Vt[((size_t)bb * 4 + 0) * NPTP + i] = bf16rtn(hh.x * nrm);
    Vt[((size_t)bb * 4 + 1) * NPTP + i] = bf16rtn(hh.y * nrm);
    Vt[((size_t)bb * 4 + 2) * NPTP + i] = bf16rtn(hh.z * nrm);
    Vt[((size_t)bb * 4 + 3) * NPTP + i] = bf16rtn(hh.w * nrm);
    G4[idx] = make_float4((1.0f - hh.x) * nrm, (1.0f - hh.y) * nrm,
                          (1.0f - hh.z) * nrm, (1.0f - hh.w) * nrm);
  } else {
    Vt[((size_t)bb * 4 + 0) * NPTP + i] = 0;
    Vt[((size_t)bb * 4 + 1) * NPTP + i] = 0;
    Vt[((size_t)bb * 4 + 2) * NPTP + i] = 0;
    Vt[((size_t)bb * 4 + 3) * NPTP + i] = 0;
    G4[idx] = make_float4(0.f, 0.f, 0.f, 0.f);
  }
}

// Pass 2: ARG as pass1; W regs 0..7 / 8..15 feed two PV mfmas D2[c][i] += Vt^T * W.
// j-permutation {0-3,8-11}/{4-7,12-15} absorbed into Vt A-frag addressing.
__global__ void __launch_bounds__(256) pass2_kernel(const short8* __restrict__ AHI,
                                                    const short8* __restrict__ ALO,
                                                    const short8* __restrict__ BHL,
                                                    const unsigned short* __restrict__ Vt,
                                                    const float4* __restrict__ G4,
                                                    float* __restrict__ partialLoss) {
  int tid = threadIdx.x, wid = tid >> 6, l = tid & 63, h = l >> 5, li = l & 31;
  int bb = blockIdx.z, ch = blockIdx.y;
  int it = blockIdx.x * 4 + wid;
  int i = it * 32 + li;
  size_t pbase = (size_t)bb * NPTP;

  short8 zer = {0, 0, 0, 0, 0, 0, 0, 0};
  short4_ zer4 = {0, 0, 0, 0};
  short8 b1 = AHI[pbase + i];
  short8 b2 = h ? zer : ALO[pbase + i];
  float4 g = G4[pbase + i];

  bool cok = li < 4;
  const unsigned short* vrow = Vt + ((size_t)bb * 4 + (cok ? li : 0)) * NPTP;

  f32x16 d2;
  #pragma unroll
  for (int r = 0; r < 16; ++r) d2[r] = 0.0f;

  int t0 = ch * TIL / JSP, t1 = (ch + 1) * TIL / JSP;
  for (int t = t0; t < t1; ++t) {
    int j32 = t * 32;
    short8 a1 = BHL[(pbase + j32 + li) * 2 + h];
    f32x16 acc;
    #pragma unroll
    for (int r = 0; r < 16; ++r) acc[r] = 0.0f;
    acc = MFMA32(a1, b1, acc);
    acc = MFMA32(a1, b2, acc);
    float w[16];
    #pragma unroll
    for (int r = 0; r < 16; ++r) w[r] = EXP2(acc[r]);

    int p[8];
    #pragma unroll
    for (int r = 0; r < 8; ++r)
      asm("v_cvt_pk_bf16_f32 %0, %1, %2" : "=v"(p[r]) : "v"(w[2*r]), "v"(w[2*r+1]));
    union { int4_ iv; short8 sv; } u1, u2;
    u1.iv = (int4_){p[0], p[1], p[2], p[3]};
    u2.iv = (int4_){p[4], p[5], p[6], p[7]};

    short4_ va = cok ? *(const short4_*)(vrow + j32 + 4*h)      : zer4;
    short4_ vb = cok ? *(const short4_*)(vrow + j32 + 8 + 4*h)  : zer4;
    short4_ vc = cok ? *(const short4_*)(vrow + j32 + 16 + 4*h) : zer4;
    short4_ vd = cok ? *(const short4_*)(vrow + j32 + 24 + 4*h) : zer4;
    short8 vf1, vf2;
    #pragma unroll
    for (int e = 0; e < 4; ++e) {
      vf1[e] = va[e]; vf1[4 + e] = vb[e];
      vf2[e] = vc[e]; vf2[4 + e] = vd[e];
    }
    d2 = MFMA32(vf1, u1.sv, d2);
    d2 = MFMA32(vf2, u2.sv, d2);
  }

  float loss = d2[0] * g.x + d2[1] * g.y + d2[2] * g.z + d2[3] * g.w;  // h=1 regs are 0
  float r = blockReduceSum(loss);
  if (tid == 0)
    partialLoss[((size_t)bb * JSP + ch) * IBLOCKS + blockIdx.x] = r;
}

__global__ void reduce_kernel(const float* __restrict__ partialLoss, int n,
                              float* __restrict__ out) {
  float v = 0.0f;
  for (int k = threadIdx.x; k < n; k += 256) v += partialLoss[k];
  float r = blockReduceSum(v);
  if (threadIdx.x == 0) out[0] = r;
}

extern "C" void kernel_launch(void* const* d_in, const int* in_sizes, int n_in,
                              void* d_out, int out_size, void* d_ws, size_t ws_size,
                              hipStream_t stream) {
  const float* I = (const float*)d_in[0];
  const float* U = (const float*)d_in[1];
  float* out = (float*)d_out;

  char* w = (char*)d_ws;
  short8* AHI = (short8*)w;          w += (size_t)B_ * NPTP * 16;
  short8* ALO = (short8*)w;          w += (size_t)B_ * NPTP * 16;
  short8* BHL = (short8*)w;          w += (size_t)B_ * NPTP * 32;
  float4* H   = (float4*)w;          w += (size_t)B_ * NPTP * 16;
  float*  part = (float*)w;          w += (size_t)B_ * JSP * NPTP * 4;
  unsigned short* Vt = (unsigned short*)w; w += (size_t)B_ * 4 * NPTP * 2;
  float4* G4  = (float4*)w;          w += (size_t)B_ * NPTP * 16;
  float*  pl  = (float*)w;           w += (size_t)B_ * JSP * IBLOCKS * 4;

  prep_kernel<<<(B_ * NPTP + 255) / 256, 256, 0, stream>>>(I, U, AHI, ALO, BHL, H);
  dim3 grid(IBLOCKS, JSP, B_);
  pass1_kernel<<<grid, 256, 0, stream>>>(AHI, ALO, BHL, part);
  finalize_kernel<<<(B_ * NPTP + 255) / 256, 256, 0, stream>>>(H, part, Vt, G4);
  pass2_kernel<<<grid, 256, 0, stream>>>(AHI, ALO, BHL, Vt, G4, pl);
  reduce_kernel<<<1, 256, 0, stream>>>(pl, B_ * JSP * IBLOCKS, out);
}